// Round 1
// baseline (737.785 us; speedup 1.0000x reference)
//
#include <hip/hip_runtime.h>
#include <hip/hip_bf16.h>

namespace {
constexpr int Bc=1, Vc=2, Tc=2, TTc=4, Nc=256, NNc=4, Dc=1, DDc=4, Fc=64;
constexpr int OTc=2, ATTc=128, Hc=32, NHc=4;
constexpr int T2c=8;
constexpr float NZEROf = 256.0f;                 // V*T2*NN*(D2-DD) zero-token kv slots
constexpr float SCALEc = 0.17677669529663687f;   // 1/sqrt(32)

// padded LDS row strides (break 32-bank aliasing)
constexpr int HS=72;    // bf16 per h row (144B, 16B aligned)
constexpr int QS=36, KS=36, VS=36;   // f32 per row
constexpr int US=66;    // upd row stride
constexpr int HIDS=132, H2S=66;

constexpr int OFF_H   = 0;        // bf16[256][72]  36864B
constexpr int OFF_Q   = 36864;    // f32 [128][36]  18432B
constexpr int OFF_K   = 55296;    // f32 [256][36]  36864B
constexpr int OFF_V   = 92160;    // f32 [256][36]  36864B
constexpr int OFF_UPD = 129024;   // f32 [128][66]  33792B -> 162816
constexpr int OFF_ML  = OFF_V;    // overlay: f32[128][2] (v dead during merge)
// epilogue overlays (h/q/k/v dead):
constexpr int OFF_HID = 0;        // f32[128][132] 67584B
constexpr int OFF_H2  = 67584;    // f32[128][66]  33792B -> 101376
constexpr int OFF_RED = 101376;   // f32[128][2][2] 2048B
constexpr int LDS_BYTES = 162816; // 159 KB < 160 KB
}

__global__ __launch_bounds__(256, 1) void fam_fused(
    const float* __restrict__ x,
    const float* __restrict__ ln1_s, const float* __restrict__ ln1_b,
    const float* __restrict__ Wq, const float* __restrict__ Wkv, const float* __restrict__ bkv,
    const float* __restrict__ Wo, const float* __restrict__ bo, const float* __restrict__ gamma,
    const float* __restrict__ ln2_s, const float* __restrict__ ln2_b,
    const float* __restrict__ W1, const float* __restrict__ b1,
    const float* __restrict__ W2, const float* __restrict__ b2,
    const float* __restrict__ gamma_mlp,
    float* __restrict__ out)
{
    __shared__ __align__(16) char smem[LDS_BYTES];
    __hip_bfloat16* sh_h = reinterpret_cast<__hip_bfloat16*>(smem + OFF_H);
    float* sh_q   = reinterpret_cast<float*>(smem + OFF_Q);
    float* sh_k   = reinterpret_cast<float*>(smem + OFF_K);
    float* sh_v   = reinterpret_cast<float*>(smem + OFF_V);
    float* sh_upd = reinterpret_cast<float*>(smem + OFF_UPD);
    float* sh_ml  = reinterpret_cast<float*>(smem + OFF_ML);

    const int tid = threadIdx.x;
    const int w = blockIdx.x;                 // ((bb*T + t)*N + n)*D + d
    const int d  = w % Dc;
    const int n  = (w / Dc) % Nc;
    const int t  = (w / (Dc*Nc)) % Tc;
    const int bb = w / (Dc*Nc*Tc);

    // ---- Phase 1: LN1 of the 256 (v,t2,nn,dd) source rows into sh_h; zero upd
    {
        const int r  = tid;
        const int v  = r >> 7;
        const int t2 = (r >> 4) & 7;
        const int nn = (r >> 2) & 3;
        const int dd = r & 3;
        int tsrc, tt;
        if (t2 < OTc)            { tsrc = t - 1; tt = t2 + (TTc - OTc); }
        else if (t2 < OTc + TTc) { tsrc = t;     tt = t2 - OTc; }
        else                     { tsrc = t + 1; tt = t2 - OTc - TTc; }
        __hip_bfloat16* hrow = sh_h + r*HS;
        if (tsrc < 0 || tsrc >= Tc) {
            #pragma unroll
            for (int f = 0; f < Fc; ++f) hrow[f] = __float2bfloat16(0.0f);
        } else {
            const size_t off = ((((size_t)(bb*Vc + v)*(Tc*TTc) + (tsrc*TTc + tt))*(Nc*NNc)
                               + (n*NNc + nn))*(Dc*DDc) + (d*DDc + dd))*Fc;
            float xv[Fc];
            #pragma unroll
            for (int f = 0; f < Fc; ++f) xv[f] = x[off + f];
            float s = 0.f;
            #pragma unroll
            for (int f = 0; f < Fc; ++f) s += xv[f];
            const float mean = s * (1.0f/Fc);
            float vs = 0.f;
            #pragma unroll
            for (int f = 0; f < Fc; ++f) { const float dl = xv[f]-mean; vs += dl*dl; }
            const float rstd = rsqrtf(vs*(1.0f/Fc) + 1e-5f);
            #pragma unroll
            for (int f = 0; f < Fc; ++f)
                hrow[f] = __float2bfloat16((xv[f]-mean)*rstd*ln1_s[f] + ln1_b[f]);
        }
        const int rr = tid & 127, hf = tid >> 7;
        #pragma unroll
        for (int j = 0; j < 32; ++j) sh_upd[rr*US + hf*32 + j] = 0.0f;
    }
    __syncthreads();

    // ---- Per-head: stage q/k/v, flash attention (2-thread kv split), upd += o@Wo
    #pragma unroll 1
    for (int nh = 0; nh < NHc; ++nh) {
        const int cb = nh*Hc;
        {   // stage q: thread -> (sq = tid&127, 16 channels)
            const int sq = tid & 127;
            const int hh0 = (tid >> 7)*16;
            const int v = sq >> 6, tt = (sq >> 4) & 3, nn = (sq >> 2) & 3, dd = sq & 3;
            const int hr = ((v*T2c + tt + OTc)*NNc + nn)*DDc + dd;
            const __hip_bfloat16* hrow = sh_h + hr*HS;
            float acc[16];
            #pragma unroll
            for (int j = 0; j < 16; ++j) acc[j] = 0.f;
            #pragma unroll 4
            for (int f = 0; f < Fc; ++f) {
                const float hv = __bfloat162float(hrow[f]);
                const float* wr = Wq + f*ATTc + cb + hh0;
                #pragma unroll
                for (int j = 0; j < 16; ++j) acc[j] += hv*wr[j];
            }
            #pragma unroll
            for (int j = 0; j < 16; ++j) sh_q[sq*QS + hh0 + j] = acc[j];
        }
        {   // stage k,v: thread -> one of 256 kv rows
            const int r = tid;
            const __hip_bfloat16* hrow = sh_h + r*HS;
            float ak[Hc], av[Hc];
            #pragma unroll
            for (int j = 0; j < Hc; ++j) { ak[j]=0.f; av[j]=0.f; }
            #pragma unroll 2
            for (int f = 0; f < Fc; ++f) {
                const float hv = __bfloat162float(hrow[f]);
                const float* wk = Wkv + f*(2*ATTc) + cb;
                #pragma unroll
                for (int j = 0; j < Hc; ++j) ak[j] += hv*wk[j];
                const float* wv = Wkv + f*(2*ATTc) + ATTc + cb;
                #pragma unroll
                for (int j = 0; j < Hc; ++j) av[j] += hv*wv[j];
            }
            #pragma unroll
            for (int j = 0; j < Hc; ++j) {
                sh_k[r*KS + j] = ak[j] + bkv[cb + j];
                sh_v[r*VS + j] = av[j] + bkv[ATTc + cb + j];
            }
        }
        __syncthreads();

        const int r = tid & 127;
        const int half = tid >> 7;
        float qv[Hc];
        #pragma unroll
        for (int j = 0; j < Hc; ++j) qv[j] = sh_q[r*QS + j];
        float m = -1e30f, l = 0.f;
        float acc[Hc];
        #pragma unroll
        for (int j = 0; j < Hc; ++j) acc[j] = 0.f;
        const int kv0 = half*128;
        #pragma unroll 2
        for (int kv = kv0; kv < kv0 + 128; ++kv) {
            const float* kr = sh_k + kv*KS;       // wave-uniform -> LDS broadcast
            float s = 0.f;
            #pragma unroll
            for (int j = 0; j < Hc; ++j) s += qv[j]*kr[j];
            s *= SCALEc;
            const float mn = fmaxf(m, s);
            const float c = __expf(m - mn);
            const float p = __expf(s - mn);
            l = l*c + p;
            const float* vr = sh_v + kv*VS;
            #pragma unroll
            for (int j = 0; j < Hc; ++j) acc[j] = acc[j]*c + p*vr[j];
            m = mn;
        }
        if (half == 0) {
            // 256 exactly-zero kv tokens (depth halo): k=bkv_k, v=bkv_v, multiplicity 256
            float s = 0.f;
            #pragma unroll
            for (int j = 0; j < Hc; ++j) s += qv[j]*bkv[cb + j];
            s *= SCALEc;
            const float mn = fmaxf(m, s);
            const float c = __expf(m - mn);
            const float p = NZEROf * __expf(s - mn);
            l = l*c + p;
            #pragma unroll
            for (int j = 0; j < Hc; ++j) acc[j] = acc[j]*c + p*bkv[ATTc + cb + j];
            m = mn;
        }
        __syncthreads();
        if (half == 1) {
            sh_ml[r*2 + 0] = m;
            sh_ml[r*2 + 1] = l;
            #pragma unroll
            for (int j = 0; j < Hc; ++j) sh_q[r*QS + j] = acc[j];
        }
        __syncthreads();
        if (half == 0) {
            const float m2 = sh_ml[r*2], l2 = sh_ml[r*2 + 1];
            const float mn = fmaxf(m, m2);
            const float c1 = __expf(m - mn), c2 = __expf(m2 - mn);
            const float inv = 1.0f / (l*c1 + l2*c2);
            #pragma unroll
            for (int j = 0; j < Hc; ++j)
                sh_q[r*QS + j] = (acc[j]*c1 + sh_q[r*QS + j]*c2)*inv;   // read-then-write, same thread
        }
        __syncthreads();
        {   // upd[r][f-range] += o_row @ Wo_head
            const int f0 = half*32;
            float ua[32];
            #pragma unroll
            for (int j = 0; j < 32; ++j) ua[j] = 0.f;
            #pragma unroll 2
            for (int i = 0; i < Hc; ++i) {
                const float ov = sh_q[r*QS + i];
                const float* wr = Wo + (cb + i)*Fc + f0;
                #pragma unroll
                for (int j = 0; j < 32; ++j) ua[j] += ov*wr[j];
            }
            #pragma unroll
            for (int j = 0; j < 32; ++j) sh_upd[r*US + f0 + j] += ua[j];
        }
        __syncthreads();
    }

    // ---- Epilogue: residual + LN2 + MLP + residual, write out
    float* sh_hid = reinterpret_cast<float*>(smem + OFF_HID);
    float* sh_h2  = reinterpret_cast<float*>(smem + OFF_H2);
    float* sh_red = reinterpret_cast<float*>(smem + OFF_RED);

    const int r = tid & 127, hf = tid >> 7, f0 = hf*32;
    const int v = r >> 6, tt = (r >> 4) & 3, nn = (r >> 2) & 3, dd = r & 3;
    const size_t xoff = ((((size_t)(bb*Vc + v)*(Tc*TTc) + (t*TTc + tt))*(Nc*NNc)
                        + (n*NNc + nn))*(Dc*DDc) + (d*DDc + dd))*Fc;

    float tv[32];
    {
        float s1 = 0.f, s2 = 0.f;
        #pragma unroll
        for (int j = 0; j < 32; ++j) {
            const int f = f0 + j;
            const float u = sh_upd[r*US + f] + bo[f];
            const float tk = x[xoff + f] + gamma[f]*u;
            tv[j] = tk;
            s1 += tk; s2 += tk*tk;
        }
        sh_red[(r*2 + hf)*2 + 0] = s1;
        sh_red[(r*2 + hf)*2 + 1] = s2;
    }
    __syncthreads();
    {
        const float a1 = sh_red[(r*2+0)*2+0] + sh_red[(r*2+1)*2+0];
        const float a2 = sh_red[(r*2+0)*2+1] + sh_red[(r*2+1)*2+1];
        const float mean = a1*(1.0f/Fc);
        const float var  = a2*(1.0f/Fc) - mean*mean;
        const float rstd = rsqrtf(var + 1e-5f);
        #pragma unroll
        for (int j = 0; j < 32; ++j) {
            const int f = f0 + j;
            sh_h2[r*H2S + f] = (tv[j]-mean)*rstd*ln2_s[f] + ln2_b[f];
        }
    }
    __syncthreads();
    {   // MLP1 + gelu(tanh approx, matches jax.nn.gelu default)
        const int a0 = hf*64;
        float ha[64];
        #pragma unroll
        for (int j = 0; j < 64; ++j) ha[j] = b1[a0 + j];
        #pragma unroll 2
        for (int f = 0; f < Fc; ++f) {
            const float hv = sh_h2[r*H2S + f];
            const float* wr = W1 + f*ATTc + a0;
            #pragma unroll
            for (int j = 0; j < 64; ++j) ha[j] += hv*wr[j];
        }
        #pragma unroll
        for (int j = 0; j < 64; ++j) {
            const float z = ha[j];
            const float u = 0.7978845608028654f*(z + 0.044715f*z*z*z);
            sh_hid[r*HIDS + a0 + j] = 0.5f*z*(1.0f + tanhf(u));
        }
    }
    __syncthreads();
    {   // MLP2 + final residual
        float oa[32];
        #pragma unroll
        for (int j = 0; j < 32; ++j) oa[j] = b2[f0 + j];
        #pragma unroll 2
        for (int a = 0; a < ATTc; ++a) {
            const float hv = sh_hid[r*HIDS + a];
            const float* wr = W2 + a*Fc + f0;
            #pragma unroll
            for (int j = 0; j < 32; ++j) oa[j] += hv*wr[j];
        }
        #pragma unroll
        for (int j = 0; j < 32; ++j)
            out[xoff + f0 + j] = tv[j] + gamma_mlp[f0 + j]*oa[j];
    }
}

extern "C" void kernel_launch(void* const* d_in, const int* in_sizes, int n_in,
                              void* d_out, int out_size, void* d_ws, size_t ws_size,
                              hipStream_t stream) {
    const float* x        = (const float*)d_in[0];
    const float* ln1_s    = (const float*)d_in[1];
    const float* ln1_b    = (const float*)d_in[2];
    const float* Wq       = (const float*)d_in[3];
    const float* Wkv      = (const float*)d_in[4];
    const float* bkv      = (const float*)d_in[5];
    const float* Wo       = (const float*)d_in[6];
    const float* bo       = (const float*)d_in[7];
    const float* gamma    = (const float*)d_in[8];
    const float* ln2_s    = (const float*)d_in[9];
    const float* ln2_b    = (const float*)d_in[10];
    const float* W1       = (const float*)d_in[11];
    const float* b1       = (const float*)d_in[12];
    const float* W2       = (const float*)d_in[13];
    const float* b2       = (const float*)d_in[14];
    const float* gamma_mlp= (const float*)d_in[15];
    float* out = (float*)d_out;

    dim3 grid(Bc*Tc*Nc*Dc);   // 512 windows
    dim3 block(256);
    hipLaunchKernelGGL(fam_fused, grid, block, 0, stream,
                       x, ln1_s, ln1_b, Wq, Wkv, bkv, Wo, bo, gamma,
                       ln2_s, ln2_b, W1, b1, W2, b2, gamma_mlp, out);
}